// Round 16
// baseline (186.449 us; speedup 1.0000x reference)
//
#include <hip/hip_runtime.h>
#include <hip/hip_bf16.h>
#include <math.h>

typedef __bf16 bf16;
typedef __attribute__((ext_vector_type(8))) __bf16 bf16x8;
typedef __attribute__((ext_vector_type(4))) __bf16 bf16x4;
typedef __attribute__((ext_vector_type(4))) float f32x4;
typedef __attribute__((ext_vector_type(2))) float f32x2;
typedef __attribute__((ext_vector_type(4))) short shortx4;

#define NTOK 4096
#define DIM  320
#define HEADS 8
#define DHEAD 40
#define NCTX 77
#define CTXD 768
#define IFF  1280

#define QSCALE (0.15811388300841897f * 1.4426950408889634f)  // 40^-0.5 * log2(e)

__device__ __forceinline__ bf16x8 bzero8() {
    bf16x8 v;
#pragma unroll
    for (int e = 0; e < 8; ++e) v[e] = (bf16)0.0f;
    return v;
}

__device__ __forceinline__ void gld_lds16(const void* g, void* l) {
    __builtin_amdgcn_global_load_lds(
        (const __attribute__((address_space(1))) void*)g,
        (__attribute__((address_space(3))) void*)l, 16, 0, 0);
}

// ---------------- LayerNorm body (flat 256 threads, 4 rows/block) ------------
__device__ __forceinline__ void ln_body(const float* __restrict__ X, const float* __restrict__ g,
                                        const float* __restrict__ b, bf16* __restrict__ Y, int row) {
    int lane = threadIdx.x & 63;
    const float* xr = X + (size_t)row * DIM;
    float v[5];
    float sum = 0.f;
#pragma unroll
    for (int c = 0; c < 5; ++c) { v[c] = xr[c * 64 + lane]; sum += v[c]; }
#pragma unroll
    for (int off = 1; off < 64; off <<= 1) sum += __shfl_xor(sum, off);
    float mu = sum * (1.f / 320.f);
    float vs = 0.f;
#pragma unroll
    for (int c = 0; c < 5; ++c) { float d = v[c] - mu; vs += d * d; }
#pragma unroll
    for (int off = 1; off < 64; off <<= 1) vs += __shfl_xor(vs, off);
    float rs = rsqrtf(vs * (1.f / 320.f) + 1e-5f);
    bf16* yr = Y + (size_t)row * DIM;
#pragma unroll
    for (int c = 0; c < 5; ++c)
        yr[c * 64 + lane] = (bf16)((v[c] - mu) * rs * g[c * 64 + lane] + b[c * 64 + lane]);
}

__global__ __launch_bounds__(256)
void layernorm_kernel(const float* __restrict__ X, const float* __restrict__ g,
                      const float* __restrict__ b, bf16* __restrict__ Y) {
    ln_body(X, g, b, Y, blockIdx.x * 4 + (threadIdx.x >> 6));
}

// ---------------- fused preprocessing: transposes + ctx convert + LN1 --------
#define PRE_TILES 2280
#define CONV_BLOCKS 231
#define LN1_BLOCKS 1024

struct PreJob { const float* src; bf16* dst; int K, N, ntx, tile0, perm; };
struct PreTab { PreJob j[10]; };

__global__ __launch_bounds__(256)
void preprocess_all(PreTab P, const float* __restrict__ ctx, bf16* __restrict__ ctxb,
                    const float* __restrict__ x, const float* __restrict__ n1_g,
                    const float* __restrict__ n1_b, bf16* __restrict__ lnbuf) {
    const int b = blockIdx.x;
    const int t = threadIdx.x;
    if (b >= PRE_TILES + CONV_BLOCKS) {
        ln_body(x, n1_g, n1_b, lnbuf, (b - PRE_TILES - CONV_BLOCKS) * 4 + (t >> 6));
        return;
    }
    if (b >= PRE_TILES) {
        int i = (b - PRE_TILES) * 256 + t;
        if (i < NCTX * CTXD) ctxb[i] = (bf16)ctx[i];
        return;
    }
    const int tx = t & 31, ty = t >> 5;
    int ji = 0;
#pragma unroll
    for (int k = 1; k < 10; ++k)
        if (b >= P.j[k].tile0) ji = k;
    const PreJob jb = P.j[ji];
    const int local = b - jb.tile0;
    const int n0 = (local % jb.ntx) * 32;
    const int k0 = (local / jb.ntx) * 32;

    __shared__ float tile[32][33];
#pragma unroll
    for (int i = 0; i < 4; ++i)
        tile[ty + i * 8][tx] = jb.src[(size_t)(k0 + ty + i * 8) * jb.N + n0 + tx];
    __syncthreads();
#pragma unroll
    for (int i = 0; i < 4; ++i) {
        int n = n0 + ty + i * 8;
        int nd = jb.perm ? ((n < 1280) ? 2 * n : 2 * (n - 1280) + 1) : n;
        jb.dst[(size_t)nd * jb.K + k0 + tx] = (bf16)tile[tx][ty + i * 8];
    }
}

// ---------------- single-barrier double-buffered bf16 MFMA GEMM --------------
template <int EPI, int BM, int BN, int SWZ>
__global__ __launch_bounds__(256)
void gemm_db(const bf16* __restrict__ A, const bf16* __restrict__ Bt,
             int M, int N, int K,
             bf16* __restrict__ Y0, bf16* __restrict__ Y1, bf16* __restrict__ Y2,
             float* Yf, const float* __restrict__ bias, const float* res, int trs) {
    constexpr int ABYTES = BM * 128;
    constexpr int BBYTES = BN * 128;
    constexpr int FB = ABYTES + BBYTES;
    constexpr int WM = BM / 2;
    constexpr int WN = BN / 2;
    constexpr int MI = WM / 16;
    constexpr int NI = WN / 16;
    constexpr int ACH = BM / 32;
    constexpr int BCH = BN / 32;
    __shared__ char smem[2 * FB];
    const int t = threadIdx.x, lane = t & 63, w = t >> 6;
    const int wr = w >> 1, wc = w & 1;

    int bx = blockIdx.x, by = blockIdx.y;
    if (SWZ) {
        int gx = gridDim.x;
        int nwg = gx * gridDim.y;
        int bid = by * gx + bx;
        int s = (bid & 7) * (nwg >> 3) + (bid >> 3);
        bx = s % gx; by = s / gx;
    }
    const int m0 = bx * BM;
    const int n0 = by * BN;

    const bf16* asrc[ACH];
    const bf16* bsrc[BCH];
#pragma unroll
    for (int i = 0; i < ACH; ++i) {
        int ch = i * 256 + t;
        int row = ch >> 3, seg = (ch & 7) ^ (row & 7);
        asrc[i] = A + (size_t)(m0 + row) * K + seg * 8;
    }
#pragma unroll
    for (int i = 0; i < BCH; ++i) {
        int ch = i * 256 + t;
        int row = ch >> 3, seg = (ch & 7) ^ (row & 7);
        bsrc[i] = Bt + (size_t)(n0 + row) * K + seg * 8;
    }

    f32x4 acc[MI][NI];
#pragma unroll
    for (int mi = 0; mi < MI; ++mi)
#pragma unroll
        for (int ni = 0; ni < NI; ++ni)
#pragma unroll
            for (int r = 0; r < 4; ++r) acc[mi][ni][r] = 0.f;

    auto STAGE = [&](char* base, int k0) {
#pragma unroll
        for (int i = 0; i < ACH; ++i)
            gld_lds16(asrc[i] + k0, base + (i * 256 + w * 64) * 16);
#pragma unroll
        for (int i = 0; i < BCH; ++i)
            gld_lds16(bsrc[i] + k0, base + ABYTES + (i * 256 + w * 64) * 16);
    };

    char* cur = smem;
    char* nxt = smem + FB;
    STAGE(cur, 0);
    __syncthreads();

    for (int k0 = 0; k0 < K; k0 += 64) {
        if (k0 + 64 < K) STAGE(nxt, k0 + 64);
        bf16x8 a[MI][2], b[NI][2];
#pragma unroll
        for (int mi = 0; mi < MI; ++mi)
#pragma unroll
            for (int kh = 0; kh < 2; ++kh) {
                int row = wr * WM + mi * 16 + (lane & 15);
                a[mi][kh] = *(const bf16x8*)(cur + row * 128 +
                             ((kh * 64 + (lane >> 4) * 16) ^ ((row & 7) << 4)));
            }
#pragma unroll
        for (int ni = 0; ni < NI; ++ni)
#pragma unroll
            for (int kh = 0; kh < 2; ++kh) {
                int row = wc * WN + ni * 16 + (lane & 15);
                b[ni][kh] = *(const bf16x8*)(cur + ABYTES + row * 128 +
                             ((kh * 64 + (lane >> 4) * 16) ^ ((row & 7) << 4)));
            }
#pragma unroll
        for (int mi = 0; mi < MI; ++mi)
#pragma unroll
            for (int ni = 0; ni < NI; ++ni) {
                acc[mi][ni] = __builtin_amdgcn_mfma_f32_16x16x32_bf16(a[mi][0], b[ni][0], acc[mi][ni], 0, 0, 0);
                acc[mi][ni] = __builtin_amdgcn_mfma_f32_16x16x32_bf16(a[mi][1], b[ni][1], acc[mi][ni], 0, 0, 0);
            }
        __syncthreads();
        char* tmp = cur; cur = nxt; nxt = tmp;
    }

#pragma unroll
    for (int mi = 0; mi < MI; ++mi)
#pragma unroll
        for (int ni = 0; ni < NI; ++ni) {
            const int col = n0 + wc * WN + ni * 16 + (lane & 15);
            const int rowb = m0 + wr * WM + mi * 16 + (lane >> 4) * 4;
            if (EPI == 5) {
                if (col < 320) {
#pragma unroll
                    for (int r = 0; r < 4; ++r)
                        Y0[(size_t)(rowb + r) * 320 + col] = (bf16)(acc[mi][ni][r] * QSCALE);
                } else if (col < 640) {
#pragma unroll
                    for (int r = 0; r < 4; ++r)
                        Y1[(size_t)(rowb + r) * 320 + (col - 320)] = (bf16)acc[mi][ni][r];
                } else {
                    bf16x4 tv;
#pragma unroll
                    for (int r = 0; r < 4; ++r) tv[r] = (bf16)acc[mi][ni][r];
                    *(bf16x4*)(Y2 + (size_t)(col - 640) * trs + rowb) = tv;
                }
            } else if (EPI == 7) {
                int bidx = (col & 1) ? (1280 + (col >> 1)) : (col >> 1);
                float bc = bias[bidx];
#pragma unroll
                for (int r = 0; r < 4; ++r) {
                    float v = acc[mi][ni][r] + bc;
                    float other = __shfl_xor(v, 1);
                    if (!(col & 1)) {
                        float gl = 0.5f * other * (1.f + erff(other * 0.70710678118654752f));
                        Y0[(size_t)(rowb + r) * 1280 + (col >> 1)] = (bf16)(v * gl);
                    }
                }
            } else {
#pragma unroll
                for (int r = 0; r < 4; ++r) {
                    int row = rowb + r;
                    if (row < M) {
                        float v = acc[mi][ni][r];
                        if (EPI == 4) Y0[(size_t)row * N + col] = (bf16)(v * QSCALE);
                        else Yf[(size_t)row * N + col] = v + bias[col] + res[(size_t)row * N + col];
                    }
                }
            }
        }
}

// ---------------- fused LN2 + cross-KV small GEMM (one launch) ---------------
__global__ __launch_bounds__(256)
void ln2_plus_cross(const float* __restrict__ X, const float* __restrict__ g,
                    const float* __restrict__ bb, bf16* __restrict__ Y,
                    const bf16* __restrict__ A, const bf16* __restrict__ Bt,
                    bf16* __restrict__ Y0, bf16* __restrict__ Y2, int trs) {
    __shared__ char smem[24 * 1024];
    if (blockIdx.x < 1024) {
        ln_body(X, g, bb, Y, blockIdx.x * 4 + (threadIdx.x >> 6));
        return;
    }
    const int M = NCTX, K = CTXD;
    const int t = threadIdx.x;
    const int lane = t & 63;
    const int w = t >> 6;
    const int wr = w >> 1, wc = w & 1;
    const int n0 = (blockIdx.x - 1024) * 64;

    f32x4 acc[4][2];
#pragma unroll
    for (int mi = 0; mi < 4; ++mi)
#pragma unroll
        for (int ni = 0; ni < 2; ++ni)
#pragma unroll
            for (int r = 0; r < 4; ++r) acc[mi][ni][r] = 0.f;

    for (int k0 = 0; k0 < K; k0 += 64) {
#pragma unroll
        for (int i = 0; i < 4; ++i) {
            int c = t + i * 256;
            int row = c >> 3, seg = c & 7;
            bf16x8 v = bzero8();
            if (row < M) v = *(const bf16x8*)(A + (size_t)row * K + k0 + seg * 8);
            *(bf16x8*)(smem + row * 128 + ((seg * 16) ^ ((row & 7) << 4))) = v;
        }
#pragma unroll
        for (int i = 0; i < 2; ++i) {
            int c = t + i * 256;
            int row = c >> 3, seg = c & 7;
            bf16x8 v = *(const bf16x8*)(Bt + (size_t)(n0 + row) * K + k0 + seg * 8);
            *(bf16x8*)(smem + 16 * 1024 + row * 128 + ((seg * 16) ^ ((row & 7) << 4))) = v;
        }
        __syncthreads();

        bf16x8 a[4][2], bfr[2][2];
#pragma unroll
        for (int mi = 0; mi < 4; ++mi)
#pragma unroll
            for (int kh = 0; kh < 2; ++kh) {
                int row = wr * 64 + mi * 16 + (lane & 15);
                a[mi][kh] = *(const bf16x8*)(smem + row * 128 +
                             ((kh * 64 + (lane >> 4) * 16) ^ ((row & 7) << 4)));
            }
#pragma unroll
        for (int ni = 0; ni < 2; ++ni)
#pragma unroll
            for (int kh = 0; kh < 2; ++kh) {
                int row = wc * 32 + ni * 16 + (lane & 15);
                bfr[ni][kh] = *(const bf16x8*)(smem + 16 * 1024 + row * 128 +
                               ((kh * 64 + (lane >> 4) * 16) ^ ((row & 7) << 4)));
            }
#pragma unroll
        for (int mi = 0; mi < 4; ++mi)
#pragma unroll
            for (int ni = 0; ni < 2; ++ni) {
                acc[mi][ni] = __builtin_amdgcn_mfma_f32_16x16x32_bf16(a[mi][0], bfr[ni][0], acc[mi][ni], 0, 0, 0);
                acc[mi][ni] = __builtin_amdgcn_mfma_f32_16x16x32_bf16(a[mi][1], bfr[ni][1], acc[mi][ni], 0, 0, 0);
            }
        __syncthreads();
    }

#pragma unroll
    for (int mi = 0; mi < 4; ++mi)
#pragma unroll
        for (int ni = 0; ni < 2; ++ni) {
            const int col = n0 + wc * 32 + ni * 16 + (lane & 15);
            const int rowb = wr * 64 + mi * 16 + (lane >> 4) * 4;
            if (col < 320) {
#pragma unroll
                for (int r = 0; r < 4; ++r)
                    if (rowb + r < M) Y0[(size_t)(rowb + r) * 320 + col] = (bf16)acc[mi][ni][r];
            } else {
                bf16x4 tv;
#pragma unroll
                for (int r = 0; r < 4; ++r) tv[r] = (bf16)acc[mi][ni][r];
                *(bf16x4*)(Y2 + (size_t)(col - 320) * trs + rowb) = tv;
            }
        }
}

// ---------------- flash attention v10: 2 q-groups per wave -------------------
// Same proven machinery as v9 (KVT=64, gld_lds staging, ones-row l-sum,
// defer-max, unconditional kb1, bf16 partials). Each wave now serves 32 q-rows
// (groups at +0 and +64): K/V fragment loads, staging, barriers amortized 2x.
#define KVT 64
#define KBYTES 5120    // 64*80
#define VBYTES 6144    // 48*128
#define FBUF (KBYTES + VBYTES)

template <int DIRECT>
__global__ __launch_bounds__(256, 4)
void flash_attn10(const bf16* __restrict__ Qg, const bf16* __restrict__ Kg,
                  const bf16* __restrict__ VTg, bf16* __restrict__ O,
                  bf16* __restrict__ Opart, float* __restrict__ MLpart,
                  int nkv, int vstride, int tiles_per_split) {
    __shared__ char smem[2 * FBUF];   // 22528 B
    const int t = threadIdx.x, lane = t & 63, w = t >> 6;
    const int g = lane >> 4, q = lane & 15;
    const int h = blockIdx.y, split = blockIdx.z;
    const int qbA = blockIdx.x * 128 + w * 16;   // group A rows
    const int qbB = qbA + 64;                    // group B rows

    const int ntiles = (nkv + KVT - 1) / KVT;
    const int tt0 = split * tiles_per_split;
    int tt1 = tt0 + tiles_per_split;
    if (tt1 > ntiles) tt1 = ntiles;

    // ones-row init: LDS V rows 40-47 of BOTH buffers (row 40 = 1.0 -> l in accO)
    if (t < 128) {
        bf16x8 v = bzero8();
        if (((t & 63) >> 3) == 0) {
#pragma unroll
            for (int e = 0; e < 8; ++e) v[e] = (bf16)1.0f;
        }
        *(bf16x8*)(smem + (t >> 6) * FBUF + KBYTES + 5120 + (t & 63) * 16) = v;
    }

    // staging slots: w0: K0 K1 K2 | w1: K3 K4 V0 | w2: V1 V2 V3 | w3: V4
    const int nslot = (w == 3) ? 1 : 3;
    const bf16* srcp[3];
    int dstoff[3], sstep[3];
#pragma unroll
    for (int s = 0; s < 3; ++s) {
        int id = w * 3 + s;
        if (id < 5) {
            int c16 = id * 64 + lane;
            int row = c16 / 5, seg = c16 - row * 5;
            srcp[s] = Kg + (size_t)(tt0 * KVT + row) * DIM + h * DHEAD + seg * 8;
            sstep[s] = KVT * DIM;
            dstoff[s] = id * 1024;
        } else {
            int vv = id - 5;
            int c16 = vv * 64 + lane;
            int row = c16 >> 3, seg = (c16 & 7) ^ (row & 7);   // pre-swizzled source
            srcp[s] = VTg + (size_t)(h * DHEAD + row) * vstride + tt0 * KVT + seg * 8;
            sstep[s] = KVT;
            dstoff[s] = KBYTES + vv * 1024;
        }
    }

#define STAGE(BUFOFF)                                                     \
    do {                                                                  \
        _Pragma("unroll")                                                 \
        for (int s = 0; s < 3; ++s) {                                     \
            if (s < nslot) {                                              \
                gld_lds16(srcp[s], smem + (BUFOFF) + dstoff[s]);          \
                srcp[s] += sstep[s];                                      \
            }                                                             \
        }                                                                 \
    } while (0)

    // Q fragments direct from global (qf1 zero for g>0 lanes)
    bf16x8 qf0a = *(const bf16x8*)(Qg + (size_t)(qbA + q) * DIM + h * DHEAD + g * 8);
    bf16x8 qf0b = *(const bf16x8*)(Qg + (size_t)(qbB + q) * DIM + h * DHEAD + g * 8);
    bf16x8 qf1a = bzero8(), qf1b = bzero8();
    if (g == 0) {
        qf1a = *(const bf16x8*)(Qg + (size_t)(qbA + q) * DIM + h * DHEAD + 32);
        qf1b = *(const bf16x8*)(Qg + (size_t)(qbB + q) * DIM + h * DHEAD + 32);
    }

    f32x4 accA[3], accB[3];
#pragma unroll
    for (int dt = 0; dt < 3; ++dt)
#pragma unroll
        for (int r = 0; r < 4; ++r) { accA[dt][r] = 0.f; accB[dt][r] = 0.f; }
    float mA = -1e30f, mB = -1e30f;

    const int swv = (q & 7) << 4;

#define TILE_BODY(KSC, J0)                                                        \
    do {                                                                          \
        const char* Ks_ = (KSC);                                                  \
        const char* Vs_ = Ks_ + KBYTES;                                           \
        const char* kb0b = Ks_ + q * 80 + g * 16;                                 \
        const char* kb1b = Ks_ + q * 80 + 64;                                     \
        f32x4 sa[4], sb[4];                                                       \
        __builtin_amdgcn_s_setprio(1);                                            \
        _Pragma("unroll")                                                         \
        for (int jt = 0; jt < 4; ++jt) {                                          \
            bf16x8 kb0 = *(const bf16x8*)(kb0b + jt * 1280);                      \
            bf16x8 kb1 = *(const bf16x8*)(kb1b + jt * 1280);                      \
            f32x4 za, zb;                                                         \
            _Pragma("unroll") for (int r = 0; r < 4; ++r) { za[r] = 0.f; zb[r] = 0.f; } \
            za = __builtin_amdgcn_mfma_f32_16x16x32_bf16(kb0, qf0a, za, 0, 0, 0); \
            za = __builtin_amdgcn_mfma_f32_16x16x32_bf16(kb1, qf1a, za, 0, 0, 0); \
            zb = __builtin_amdgcn_mfma_f32_16x16x32_bf16(kb0, qf0b, zb, 0, 0, 0); \
            zb = __builtin_amdgcn_mfma_f32_16x16x32_bf16(kb1, qf1b, zb, 0, 0, 0); \
            sa[jt] = za; sb[jt] = zb;                                             \
        }                                                                         \
        __builtin_amdgcn_s_setprio(0);                                            \
        if ((J0) + KVT > nkv) {                                                   \
            _Pragma("unroll") for (int jt = 0; jt < 4; ++jt)                      \
            _Pragma("unroll") for (int r = 0; r < 4; ++r)                         \
                if ((J0) + jt * 16 + g * 4 + r >= nkv) { sa[jt][r] = -1e30f; sb[jt][r] = -1e30f; } \
        }                                                                         \
        {                                                                         \
            float m0_ = fmaxf(fmaxf(fmaxf(sa[0][0], sa[1][0]), sa[2][0]), sa[3][0]); \
            float m1_ = fmaxf(fmaxf(fmaxf(sa[0][1], sa[1][1]), sa[2][1]), sa[3][1]); \
            float m2_ = fmaxf(fmaxf(fmaxf(sa[0][2], sa[1][2]), sa[2][2]), sa[3][2]); \
            float m3_ = fmaxf(fmaxf(fmaxf(sa[0][3], sa[1][3]), sa[2][3]), sa[3][3]); \
            float mt = fmaxf(fmaxf(fmaxf(m0_, m1_), m2_), m3_);                   \
            mt = fmaxf(mt, __shfl_xor(mt, 16));                                   \
            mt = fmaxf(mt, __shfl_xor(mt, 32));                                   \
            if (!__all(mt <= mA + 8.f)) {                                         \
                float mnew = fmaxf(mA, mt);                                       \
                float f = exp2f(mA - mnew);                                       \
                mA = mnew;                                                        \
                _Pragma("unroll") for (int dt = 0; dt < 3; ++dt)                  \
                _Pragma("unroll") for (int r = 0; r < 4; ++r) accA[dt][r] *= f;   \
            }                                                                     \
        }                                                                         \
        {                                                                         \
            float m0_ = fmaxf(fmaxf(fmaxf(sb[0][0], sb[1][0]), sb[2][0]), sb[3][0]); \
            float m1_ = fmaxf(fmaxf(fmaxf(sb[0][1], sb[1][1]), sb[2][1]), sb[3][1]); \
            float m2_ = fmaxf(fmaxf(fmaxf(sb[0][2], sb[1][2]), sb[2][2]), sb[3][2]); \
            float m3_ = fmaxf(fmaxf(fmaxf(sb[0][3], sb[1][3]), sb[2][3]), sb[3][3]); \
            float mt = fmaxf(fmaxf(fmaxf(m0_, m1_), m2_), m3_);                   \
            mt = fmaxf(mt, __shfl_xor(mt, 16));                                   \
            mt = fmaxf(mt, __shfl_xor(mt, 32));                                   \
            if (!__all(mt <= mB + 8.f)) {                                         \
                float mnew = fmaxf(mB, mt);                                       \
                float f = exp2f(mB - mnew);                                       \
                mB = mnew;                                                        \
                _Pragma("unroll") for (int dt = 0; dt < 3; ++dt)                  \
                _Pragma("unroll") for (int r = 0; r < 4; ++r) accB[dt][r] *= f;   \
            }                                                                     \
        }                                                                         \
        union PU { bf16x4 hv; shortx4 sv; } pkA[4], pkB[4];                       \
        _Pragma("unroll") for (int jt = 0; jt < 4; ++jt) {                        \
            bf16x4 ha, hb;                                                        \
            _Pragma("unroll") for (int r = 0; r < 4; ++r) {                       \
                ha[r] = (bf16)exp2f(sa[jt][r] - mA);                              \
                hb[r] = (bf16)exp2f(sb[jt][r] - mB);                              \
            }                                                                     \
            pkA[jt].hv = ha; pkB[jt].hv = hb;                                     \
        }                                                                         \
        __builtin_amdgcn_s_setprio(1);                                            \
        const char* vqb = Vs_ + q * 128;                                          \
        _Pragma("unroll") for (int jt = 0; jt < 4; ++jt) {                        \
            const char* vj = vqb + ((jt * 32 + g * 8) ^ swv);                     \
            _Pragma("unroll") for (int dt = 0; dt < 3; ++dt) {                    \
                shortx4 vb = *(const shortx4*)(vj + dt * 2048);                   \
                accA[dt] = __builtin_amdgcn_mfma_f32_16x16x16bf16_1k(             \
                               vb, pkA[jt].sv, accA[dt], 0, 0, 0);                \
                accB[dt] = __builtin_amdgcn_mfma_f32_16x16x16bf16_1k(             \
                               vb, pkB[jt].sv, accB[dt], 0, 0, 0);                \
            }                                                                     \
        }                                                                         \
        __builtin_amdgcn_s_setprio(0);                                            \
        __syncthreads();                                                          \
    } while (0)

    STAGE(0);
    __syncthreads();

    int tt = tt0;
    while (tt < tt1) {
        if (tt + 1 < tt1) STAGE(FBUF);
        TILE_BODY(smem, tt * KVT);
        ++tt;
        if (tt >= tt1) break;
        if (tt + 1 < tt1) STAGE(0);
        TILE_BODY(smem + FBUF, tt * KVT);
        ++tt;
    }
#undef TILE_BODY
#undef STAGE

    // l = O^T row 40 (ones row), held by lane 32+q at acc[2][0]
    float lA = __shfl(accA[2][0], 32 + q);
    float lB = __shfl(accB[2][0], 32 + q);

    if (DIRECT) {
        float invA = 1.f / lA, invB = 1.f / lB;
#pragma unroll
        for (int dt = 0; dt < 3; ++dt) {
            if (dt < 2 || g < 2) {
                bf16x4 oa, ob;
#pragma unroll
                for (int r = 0; r < 4; ++r) {
                    oa[r] = (bf16)(accA[dt][r] * invA);
                    ob[r] = (bf16)(accB[dt][r] * invB);
                }
                *(bf16x4*)(O + (size_t)(qbA + q) * DIM + h * DHEAD + dt * 16 + g * 4) = oa;
                *(bf16x4*)(O + (size_t)(qbB + q) * DIM + h * DHEAD + dt * 16 + g * 4) = ob;
            }
        }
    } else {
        size_t rowA = (size_t)(split * HEADS + h) * NTOK + qbA + q;
        size_t rowB = rowA + 64;
#pragma unroll
        for (int dt = 0; dt < 3; ++dt) {
            if (dt < 2 || g < 2) {
                bf16x4 oa, ob;
#pragma unroll
                for (int r = 0; r < 4; ++r) {
                    oa[r] = (bf16)accA[dt][r];
                    ob[r] = (bf16)accB[dt][r];
                }
                *(bf16x4*)(Opart + rowA * 40 + dt * 16 + g * 4) = oa;
                *(bf16x4*)(Opart + rowB * 40 + dt * 16 + g * 4) = ob;
            }
        }
        if (g == 2) {
            f32x2 mla; mla[0] = mA; mla[1] = accA[2][0];
            f32x2 mlb; mlb[0] = mB; mlb[1] = accB[2][0];
            *(f32x2*)(MLpart + rowA * 2) = mla;
            *(f32x2*)(MLpart + rowB * 2) = mlb;
        }
    }
}

// ---------------- combine 4 KV-splits (bf16 partials) ----------------
__global__ __launch_bounds__(256)
void flash_combine(const bf16* __restrict__ Opart, const float* __restrict__ MLpart,
                   bf16* __restrict__ O) {
    int idx = blockIdx.x * 256 + threadIdx.x;  // 4096*40
    int qi = idx / 40, c = idx - qi * 40;
    int h = c / 5, c8 = c - h * 5;
    float mv[4], lv[4];
    float M = -1e30f;
#pragma unroll
    for (int s = 0; s < 4; ++s) {
        f32x2 ml = *(const f32x2*)(MLpart + ((size_t)(s * HEADS + h) * NTOK + qi) * 2);
        mv[s] = ml[0]; lv[s] = ml[1];
        M = fmaxf(M, ml[0]);
    }
    float wgt[4], denom = 0.f;
#pragma unroll
    for (int s = 0; s < 4; ++s) { wgt[s] = exp2f(mv[s] - M); denom += wgt[s] * lv[s]; }
    float inv = 1.f / denom;
    float o[8];
#pragma unroll
    for (int e = 0; e < 8; ++e) o[e] = 0.f;
#pragma unroll
    for (int s = 0; s < 4; ++s) {
        bf16x8 op = *(const bf16x8*)(Opart + ((size_t)(s * HEADS + h) * NTOK + qi) * 40 + c8 * 8);
#pragma unroll
        for (int e = 0; e < 8; ++e) o[e] += wgt[s] * (float)op[e];
    }
    bf16x8 ov;
#pragma unroll
    for (int e = 0; e < 8; ++e) ov[e] = (bf16)(o[e] * inv);
    *(bf16x8*)(O + (size_t)qi * DIM + h * DHEAD + c8 * 8) = ov;
}

// ---------------- launch ----------------
extern "C" void kernel_launch(void* const* d_in, const int* in_sizes, int n_in,
                              void* d_out, int out_size, void* d_ws, size_t ws_size,
                              hipStream_t stream) {
    const float* x     = (const float*)d_in[0];
    const float* ctx   = (const float*)d_in[1];
    const float* n1_g  = (const float*)d_in[2];
    const float* n1_b  = (const float*)d_in[3];
    const float* a1_wq = (const float*)d_in[4];
    const float* a1_wk = (const float*)d_in[5];
    const float* a1_wv = (const float*)d_in[6];
    const float* a1_wo = (const float*)d_in[7];
    const float* a1_bo = (const float*)d_in[8];
    const float* n2_g  = (const float*)d_in[9];
    const float* n2_b  = (const float*)d_in[10];
    const float* a2_wq = (const float*)d_in[11];
    const float* a2_wk = (const float*)d_in[12];
    const float* a2_wv = (const float*)d_in[13];
    const float* a2_wo = (const float*)d_in[14];
    const float* a2_bo = (const float*)d_in[15];
    const float* n3_g  = (const float*)d_in[16];
    const float* n3_b  = (const float*)d_in[17];
    const float* ff_w1 = (const float*)d_in[18];
    const float* ff_b1 = (const float*)d_in[19];
    const float* ff_w2 = (const float*)d_in[20];
    const float* ff_b2 = (const float*)d_in[21];

    char* ws = (char*)d_ws;
    size_t off = 0;
    auto alloc = [&](size_t bytes) -> char* {
        char* p = ws + off;
        off += (bytes + 255) & ~(size_t)255;
        return p;
    };
    bf16* lnbuf  = (bf16*)alloc((size_t)NTOK * DIM * 2);
    bf16* qbuf   = (bf16*)alloc((size_t)NTOK * DIM * 2);
    bf16* kbuf   = (bf16*)alloc((size_t)NTOK * DIM * 2);
    bf16* vtbuf  = (bf16*)alloc((size_t)DIM * NTOK * 2);   // [320 d][4096 tok]
    bf16* abuf   = (bf16*)alloc((size_t)NTOK * DIM * 2);
    bf16* hbuf   = (bf16*)alloc((size_t)NTOK * 2 * IFF * 2);  // Opart alias only
    bf16* gbuf   = (bf16*)alloc((size_t)NTOK * IFF * 2);
    bf16* ctxb   = (bf16*)alloc((size_t)NCTX * CTXD * 2);
    bf16* k2buf  = (bf16*)alloc((size_t)128 * DIM * 2);
    bf16* vt2buf = (bf16*)alloc((size_t)DIM * 128 * 2);
    bf16* wqkvT  = (bf16*)alloc((size_t)960 * DIM * 2);
    bf16* woT    = (bf16*)alloc((size_t)DIM * DIM * 2);
    bf16* q2T    = (bf16*)alloc((size_t)DIM * DIM * 2);
    bf16* wkv2T  = (bf16*)alloc((size_t)640 * CTXD * 2);
    bf16* o2T    = (bf16*)alloc((size_t)DIM * DIM * 2);
    bf16* w1T    = (bf16*)alloc((size_t)2 * IFF * DIM * 2);
    bf16* w2T    = (bf16*)alloc((size_t)IFF * DIM * 2);
    float* out   = (float*)d_out;

    bf16*  Opart  = (bf16*)hbuf;    // 4*8*4096*40 bf16 = 10.5 MB
    float* MLpart = (float*)gbuf;   // consumed by combine before FF1 writes gbuf

    // ---- fused preprocessing + LN1 (1 launch) ----
    {
        PreTab P;
        auto set = [&](int i, const float* s, bf16* d, int K, int N, int tile0, int perm) {
            P.j[i].src = s; P.j[i].dst = d; P.j[i].K = K; P.j[i].N = N;
            P.j[i].ntx = N / 32; P.j[i].tile0 = tile0; P.j[i].perm = perm;
        };
        set(0, a1_wq, wqkvT,                        320, 320,    0, 0);
        set(1, a1_wk, wqkvT + (size_t)320 * 320,    320, 320,  100, 0);
        set(2, a1_wv, wqkvT + (size_t)640 * 320,    320, 320,  200, 0);
        set(3, a1_wo, woT,                          320, 320,  300, 0);
        set(4, a2_wq, q2T,                          320, 320,  400, 0);
        set(5, a2_wo, o2T,                          320, 320,  500, 0);
        set(6, a2_wk, wkv2T,                        768, 320,  600, 0);
        set(7, a2_wv, wkv2T + (size_t)320 * 768,    768, 320,  840, 0);
        set(8, ff_w1, w1T,                          320, 2560, 1080, 1);
        set(9, ff_w2, w2T,                          1280, 320, 1880, 0);
        preprocess_all<<<PRE_TILES + CONV_BLOCKS + LN1_BLOCKS, 256, 0, stream>>>(
            P, ctx, ctxb, x, n1_g, n1_b, lnbuf);
    }

    // ---- self-attention ----
    gemm_db<5, 128, 64, 1><<<dim3(32, 15), 256, 0, stream>>>(lnbuf, wqkvT, NTOK, 960, DIM,
                                                             qbuf, kbuf, vtbuf, nullptr, nullptr, nullptr, NTOK);
    flash_attn10<0><<<dim3(32, 8, 4), 256, 0, stream>>>(qbuf, kbuf, vtbuf, nullptr,
                                                        Opart, MLpart, NTOK, NTOK, 16);
    flash_combine<<<640, 256, 0, stream>>>(Opart, MLpart, abuf);
    gemm_db<2, 64, 64, 1><<<dim3(64, 5), 256, 0, stream>>>(abuf, woT, NTOK, DIM, DIM,
                                                           nullptr, nullptr, nullptr, out, a1_bo, x, 0);

    // ---- cross-attention (LN2 + cross-KV fused into one launch) ----
    ln2_plus_cross<<<1034, 256, 0, stream>>>(out, n2_g, n2_b, lnbuf,
                                             ctxb, wkv2T, k2buf, vt2buf, 128);
    gemm_db<4, 64, 64, 1><<<dim3(64, 5), 256, 0, stream>>>(lnbuf, q2T, NTOK, DIM, DIM,
                                                           qbuf, nullptr, nullptr, nullptr, nullptr, nullptr, 0);
    flash_attn10<1><<<dim3(32, 8, 1), 256, 0, stream>>>(qbuf, k2buf, vt2buf, abuf,
                                                        nullptr, nullptr, NCTX, 128, 2);
    gemm_db<2, 64, 64, 1><<<dim3(64, 5), 256, 0, stream>>>(abuf, o2T, NTOK, DIM, DIM,
                                                           nullptr, nullptr, nullptr, out, a2_bo, out, 0);

    // ---- GEGLU FF (geglu fused into FF1 epilogue) ----
    layernorm_kernel<<<1024, 256, 0, stream>>>(out, n3_g, n3_b, lnbuf);
    gemm_db<7, 128, 64, 1><<<dim3(32, 40), 256, 0, stream>>>(lnbuf, w1T, NTOK, 2 * IFF, DIM,
                                                             gbuf, nullptr, nullptr, nullptr, ff_b1, nullptr, 0);
    gemm_db<2, 64, 64, 1><<<dim3(64, 5), 256, 0, stream>>>(gbuf, w2T, NTOK, DIM, IFF,
                                                           nullptr, nullptr, nullptr, out, ff_b2, out, 0);
}

// Round 17
// 179.559 us; speedup vs baseline: 1.0384x; 1.0384x over previous
//
#include <hip/hip_runtime.h>
#include <hip/hip_bf16.h>
#include <math.h>

typedef __bf16 bf16;
typedef __attribute__((ext_vector_type(8))) __bf16 bf16x8;
typedef __attribute__((ext_vector_type(4))) __bf16 bf16x4;
typedef __attribute__((ext_vector_type(4))) float f32x4;
typedef __attribute__((ext_vector_type(2))) float f32x2;
typedef __attribute__((ext_vector_type(4))) short shortx4;

#define NTOK 4096
#define DIM  320
#define HEADS 8
#define DHEAD 40
#define NCTX 77
#define CTXD 768
#define IFF  1280

#define QSCALE (0.15811388300841897f * 1.4426950408889634f)  // 40^-0.5 * log2(e)

__device__ __forceinline__ bf16x8 bzero8() {
    bf16x8 v;
#pragma unroll
    for (int e = 0; e < 8; ++e) v[e] = (bf16)0.0f;
    return v;
}

__device__ __forceinline__ void gld_lds16(const void* g, void* l) {
    __builtin_amdgcn_global_load_lds(
        (const __attribute__((address_space(1))) void*)g,
        (__attribute__((address_space(3))) void*)l, 16, 0, 0);
}

// ---------------- LayerNorm body (flat 256 threads, 4 rows/block) ------------
__device__ __forceinline__ void ln_body(const float* __restrict__ X, const float* __restrict__ g,
                                        const float* __restrict__ b, bf16* __restrict__ Y, int row) {
    int lane = threadIdx.x & 63;
    const float* xr = X + (size_t)row * DIM;
    float v[5];
    float sum = 0.f;
#pragma unroll
    for (int c = 0; c < 5; ++c) { v[c] = xr[c * 64 + lane]; sum += v[c]; }
#pragma unroll
    for (int off = 1; off < 64; off <<= 1) sum += __shfl_xor(sum, off);
    float mu = sum * (1.f / 320.f);
    float vs = 0.f;
#pragma unroll
    for (int c = 0; c < 5; ++c) { float d = v[c] - mu; vs += d * d; }
#pragma unroll
    for (int off = 1; off < 64; off <<= 1) vs += __shfl_xor(vs, off);
    float rs = rsqrtf(vs * (1.f / 320.f) + 1e-5f);
    bf16* yr = Y + (size_t)row * DIM;
#pragma unroll
    for (int c = 0; c < 5; ++c)
        yr[c * 64 + lane] = (bf16)((v[c] - mu) * rs * g[c * 64 + lane] + b[c * 64 + lane]);
}

__global__ __launch_bounds__(256)
void layernorm_kernel(const float* __restrict__ X, const float* __restrict__ g,
                      const float* __restrict__ b, bf16* __restrict__ Y) {
    ln_body(X, g, b, Y, blockIdx.x * 4 + (threadIdx.x >> 6));
}

// ---------------- fused preprocessing: transposes + ctx convert + LN1 --------
#define PRE_TILES 2280
#define CONV_BLOCKS 231
#define LN1_BLOCKS 1024

struct PreJob { const float* src; bf16* dst; int K, N, ntx, tile0, perm; };
struct PreTab { PreJob j[10]; };

__global__ __launch_bounds__(256)
void preprocess_all(PreTab P, const float* __restrict__ ctx, bf16* __restrict__ ctxb,
                    const float* __restrict__ x, const float* __restrict__ n1_g,
                    const float* __restrict__ n1_b, bf16* __restrict__ lnbuf) {
    const int b = blockIdx.x;
    const int t = threadIdx.x;
    if (b >= PRE_TILES + CONV_BLOCKS) {
        ln_body(x, n1_g, n1_b, lnbuf, (b - PRE_TILES - CONV_BLOCKS) * 4 + (t >> 6));
        return;
    }
    if (b >= PRE_TILES) {
        int i = (b - PRE_TILES) * 256 + t;
        if (i < NCTX * CTXD) ctxb[i] = (bf16)ctx[i];
        return;
    }
    const int tx = t & 31, ty = t >> 5;
    int ji = 0;
#pragma unroll
    for (int k = 1; k < 10; ++k)
        if (b >= P.j[k].tile0) ji = k;
    const PreJob jb = P.j[ji];
    const int local = b - jb.tile0;
    const int n0 = (local % jb.ntx) * 32;
    const int k0 = (local / jb.ntx) * 32;

    __shared__ float tile[32][33];
#pragma unroll
    for (int i = 0; i < 4; ++i)
        tile[ty + i * 8][tx] = jb.src[(size_t)(k0 + ty + i * 8) * jb.N + n0 + tx];
    __syncthreads();
#pragma unroll
    for (int i = 0; i < 4; ++i) {
        int n = n0 + ty + i * 8;
        int nd = jb.perm ? ((n < 1280) ? 2 * n : 2 * (n - 1280) + 1) : n;
        jb.dst[(size_t)nd * jb.K + k0 + tx] = (bf16)tile[tx][ty + i * 8];
    }
}

// ---------------- single-barrier double-buffered bf16 MFMA GEMM --------------
template <int EPI, int BM, int BN, int SWZ>
__global__ __launch_bounds__(256)
void gemm_db(const bf16* __restrict__ A, const bf16* __restrict__ Bt,
             int M, int N, int K,
             bf16* __restrict__ Y0, bf16* __restrict__ Y1, bf16* __restrict__ Y2,
             float* Yf, const float* __restrict__ bias, const float* res, int trs) {
    constexpr int ABYTES = BM * 128;
    constexpr int BBYTES = BN * 128;
    constexpr int FB = ABYTES + BBYTES;
    constexpr int WM = BM / 2;
    constexpr int WN = BN / 2;
    constexpr int MI = WM / 16;
    constexpr int NI = WN / 16;
    constexpr int ACH = BM / 32;
    constexpr int BCH = BN / 32;
    __shared__ char smem[2 * FB];
    const int t = threadIdx.x, lane = t & 63, w = t >> 6;
    const int wr = w >> 1, wc = w & 1;

    int bx = blockIdx.x, by = blockIdx.y;
    if (SWZ) {
        int gx = gridDim.x;
        int nwg = gx * gridDim.y;
        int bid = by * gx + bx;
        int s = (bid & 7) * (nwg >> 3) + (bid >> 3);
        bx = s % gx; by = s / gx;
    }
    const int m0 = bx * BM;
    const int n0 = by * BN;

    const bf16* asrc[ACH];
    const bf16* bsrc[BCH];
#pragma unroll
    for (int i = 0; i < ACH; ++i) {
        int ch = i * 256 + t;
        int row = ch >> 3, seg = (ch & 7) ^ (row & 7);
        asrc[i] = A + (size_t)(m0 + row) * K + seg * 8;
    }
#pragma unroll
    for (int i = 0; i < BCH; ++i) {
        int ch = i * 256 + t;
        int row = ch >> 3, seg = (ch & 7) ^ (row & 7);
        bsrc[i] = Bt + (size_t)(n0 + row) * K + seg * 8;
    }

    f32x4 acc[MI][NI];
#pragma unroll
    for (int mi = 0; mi < MI; ++mi)
#pragma unroll
        for (int ni = 0; ni < NI; ++ni)
#pragma unroll
            for (int r = 0; r < 4; ++r) acc[mi][ni][r] = 0.f;

    auto STAGE = [&](char* base, int k0) {
#pragma unroll
        for (int i = 0; i < ACH; ++i)
            gld_lds16(asrc[i] + k0, base + (i * 256 + w * 64) * 16);
#pragma unroll
        for (int i = 0; i < BCH; ++i)
            gld_lds16(bsrc[i] + k0, base + ABYTES + (i * 256 + w * 64) * 16);
    };

    char* cur = smem;
    char* nxt = smem + FB;
    STAGE(cur, 0);
    __syncthreads();

    for (int k0 = 0; k0 < K; k0 += 64) {
        if (k0 + 64 < K) STAGE(nxt, k0 + 64);
        bf16x8 a[MI][2], b[NI][2];
#pragma unroll
        for (int mi = 0; mi < MI; ++mi)
#pragma unroll
            for (int kh = 0; kh < 2; ++kh) {
                int row = wr * WM + mi * 16 + (lane & 15);
                a[mi][kh] = *(const bf16x8*)(cur + row * 128 +
                             ((kh * 64 + (lane >> 4) * 16) ^ ((row & 7) << 4)));
            }
#pragma unroll
        for (int ni = 0; ni < NI; ++ni)
#pragma unroll
            for (int kh = 0; kh < 2; ++kh) {
                int row = wc * WN + ni * 16 + (lane & 15);
                b[ni][kh] = *(const bf16x8*)(cur + ABYTES + row * 128 +
                             ((kh * 64 + (lane >> 4) * 16) ^ ((row & 7) << 4)));
            }
#pragma unroll
        for (int mi = 0; mi < MI; ++mi)
#pragma unroll
            for (int ni = 0; ni < NI; ++ni) {
                acc[mi][ni] = __builtin_amdgcn_mfma_f32_16x16x32_bf16(a[mi][0], b[ni][0], acc[mi][ni], 0, 0, 0);
                acc[mi][ni] = __builtin_amdgcn_mfma_f32_16x16x32_bf16(a[mi][1], b[ni][1], acc[mi][ni], 0, 0, 0);
            }
        __syncthreads();
        char* tmp = cur; cur = nxt; nxt = tmp;
    }

#pragma unroll
    for (int mi = 0; mi < MI; ++mi)
#pragma unroll
        for (int ni = 0; ni < NI; ++ni) {
            const int col = n0 + wc * WN + ni * 16 + (lane & 15);
            const int rowb = m0 + wr * WM + mi * 16 + (lane >> 4) * 4;
            if (EPI == 5) {
                if (col < 320) {
#pragma unroll
                    for (int r = 0; r < 4; ++r)
                        Y0[(size_t)(rowb + r) * 320 + col] = (bf16)(acc[mi][ni][r] * QSCALE);
                } else if (col < 640) {
#pragma unroll
                    for (int r = 0; r < 4; ++r)
                        Y1[(size_t)(rowb + r) * 320 + (col - 320)] = (bf16)acc[mi][ni][r];
                } else {
                    bf16x4 tv;
#pragma unroll
                    for (int r = 0; r < 4; ++r) tv[r] = (bf16)acc[mi][ni][r];
                    *(bf16x4*)(Y2 + (size_t)(col - 640) * trs + rowb) = tv;
                }
            } else if (EPI == 7) {
                int bidx = (col & 1) ? (1280 + (col >> 1)) : (col >> 1);
                float bc = bias[bidx];
#pragma unroll
                for (int r = 0; r < 4; ++r) {
                    float v = acc[mi][ni][r] + bc;
                    float other = __shfl_xor(v, 1);
                    if (!(col & 1)) {
                        float gl = 0.5f * other * (1.f + erff(other * 0.70710678118654752f));
                        Y0[(size_t)(rowb + r) * 1280 + (col >> 1)] = (bf16)(v * gl);
                    }
                }
            } else {
#pragma unroll
                for (int r = 0; r < 4; ++r) {
                    int row = rowb + r;
                    if (row < M) {
                        float v = acc[mi][ni][r];
                        if (EPI == 4) Y0[(size_t)row * N + col] = (bf16)(v * QSCALE);
                        else Yf[(size_t)row * N + col] = v + bias[col] + res[(size_t)row * N + col];
                    }
                }
            }
        }
}

// ---------------- fused LN2 + cross-KV small GEMM (one launch) ---------------
__global__ __launch_bounds__(256)
void ln2_plus_cross(const float* __restrict__ X, const float* __restrict__ g,
                    const float* __restrict__ bb, bf16* __restrict__ Y,
                    const bf16* __restrict__ A, const bf16* __restrict__ Bt,
                    bf16* __restrict__ Y0, bf16* __restrict__ Y2, int trs) {
    __shared__ char smem[24 * 1024];
    if (blockIdx.x < 1024) {
        ln_body(X, g, bb, Y, blockIdx.x * 4 + (threadIdx.x >> 6));
        return;
    }
    const int M = NCTX, K = CTXD;
    const int t = threadIdx.x;
    const int lane = t & 63;
    const int w = t >> 6;
    const int wr = w >> 1, wc = w & 1;
    const int n0 = (blockIdx.x - 1024) * 64;

    f32x4 acc[4][2];
#pragma unroll
    for (int mi = 0; mi < 4; ++mi)
#pragma unroll
        for (int ni = 0; ni < 2; ++ni)
#pragma unroll
            for (int r = 0; r < 4; ++r) acc[mi][ni][r] = 0.f;

    for (int k0 = 0; k0 < K; k0 += 64) {
#pragma unroll
        for (int i = 0; i < 4; ++i) {
            int c = t + i * 256;
            int row = c >> 3, seg = c & 7;
            bf16x8 v = bzero8();
            if (row < M) v = *(const bf16x8*)(A + (size_t)row * K + k0 + seg * 8);
            *(bf16x8*)(smem + row * 128 + ((seg * 16) ^ ((row & 7) << 4))) = v;
        }
#pragma unroll
        for (int i = 0; i < 2; ++i) {
            int c = t + i * 256;
            int row = c >> 3, seg = c & 7;
            bf16x8 v = *(const bf16x8*)(Bt + (size_t)(n0 + row) * K + k0 + seg * 8);
            *(bf16x8*)(smem + 16 * 1024 + row * 128 + ((seg * 16) ^ ((row & 7) << 4))) = v;
        }
        __syncthreads();

        bf16x8 a[4][2], bfr[2][2];
#pragma unroll
        for (int mi = 0; mi < 4; ++mi)
#pragma unroll
            for (int kh = 0; kh < 2; ++kh) {
                int row = wr * 64 + mi * 16 + (lane & 15);
                a[mi][kh] = *(const bf16x8*)(smem + row * 128 +
                             ((kh * 64 + (lane >> 4) * 16) ^ ((row & 7) << 4)));
            }
#pragma unroll
        for (int ni = 0; ni < 2; ++ni)
#pragma unroll
            for (int kh = 0; kh < 2; ++kh) {
                int row = wc * 32 + ni * 16 + (lane & 15);
                bfr[ni][kh] = *(const bf16x8*)(smem + 16 * 1024 + row * 128 +
                               ((kh * 64 + (lane >> 4) * 16) ^ ((row & 7) << 4)));
            }
#pragma unroll
        for (int mi = 0; mi < 4; ++mi)
#pragma unroll
            for (int ni = 0; ni < 2; ++ni) {
                acc[mi][ni] = __builtin_amdgcn_mfma_f32_16x16x32_bf16(a[mi][0], bfr[ni][0], acc[mi][ni], 0, 0, 0);
                acc[mi][ni] = __builtin_amdgcn_mfma_f32_16x16x32_bf16(a[mi][1], bfr[ni][1], acc[mi][ni], 0, 0, 0);
            }
        __syncthreads();
    }

#pragma unroll
    for (int mi = 0; mi < 4; ++mi)
#pragma unroll
        for (int ni = 0; ni < 2; ++ni) {
            const int col = n0 + wc * 32 + ni * 16 + (lane & 15);
            const int rowb = wr * 64 + mi * 16 + (lane >> 4) * 4;
            if (col < 320) {
#pragma unroll
                for (int r = 0; r < 4; ++r)
                    if (rowb + r < M) Y0[(size_t)(rowb + r) * 320 + col] = (bf16)acc[mi][ni][r];
            } else {
                bf16x4 tv;
#pragma unroll
                for (int r = 0; r < 4; ++r) tv[r] = (bf16)acc[mi][ni][r];
                *(bf16x4*)(Y2 + (size_t)(col - 320) * trs + rowb) = tv;
            }
        }
}

// ---------------- flash attention v9 (proven best configuration) -------------
// KVT=64, gld_lds double-buffered staging, swapped QK^T, in-register softmax,
// ones-row l-sum, defer-max, unconditional kb1, bf16 partials.
#define KVT 64
#define KBYTES 5120    // 64*80
#define VBYTES 6144    // 48*128
#define FBUF (KBYTES + VBYTES)

template <int DIRECT>
__global__ __launch_bounds__(256, 4)
void flash_attn9(const bf16* __restrict__ Qg, const bf16* __restrict__ Kg,
                 const bf16* __restrict__ VTg, bf16* __restrict__ O,
                 bf16* __restrict__ Opart, float* __restrict__ MLpart,
                 int nkv, int vstride, int tiles_per_split) {
    __shared__ char smem[2 * FBUF];   // 22528 B
    const int t = threadIdx.x, lane = t & 63, w = t >> 6;
    const int g = lane >> 4, q = lane & 15;
    const int h = blockIdx.y, split = blockIdx.z;
    const int qb = blockIdx.x * 64 + w * 16;

    const int ntiles = (nkv + KVT - 1) / KVT;
    const int tt0 = split * tiles_per_split;
    int tt1 = tt0 + tiles_per_split;
    if (tt1 > ntiles) tt1 = ntiles;

    // ones-row init: LDS V rows 40-47 of BOTH buffers (row 40 = 1.0 -> l in accO)
    if (t < 128) {
        bf16x8 v = bzero8();
        if (((t & 63) >> 3) == 0) {
#pragma unroll
            for (int e = 0; e < 8; ++e) v[e] = (bf16)1.0f;
        }
        *(bf16x8*)(smem + (t >> 6) * FBUF + KBYTES + 5120 + (t & 63) * 16) = v;
    }

    // staging slots: w0: K0 K1 K2 | w1: K3 K4 V0 | w2: V1 V2 V3 | w3: V4
    const int nslot = (w == 3) ? 1 : 3;
    const bf16* srcp[3];
    int dstoff[3], sstep[3];
#pragma unroll
    for (int s = 0; s < 3; ++s) {
        int id = w * 3 + s;
        if (id < 5) {
            int c16 = id * 64 + lane;
            int row = c16 / 5, seg = c16 - row * 5;
            srcp[s] = Kg + (size_t)(tt0 * KVT + row) * DIM + h * DHEAD + seg * 8;
            sstep[s] = KVT * DIM;
            dstoff[s] = id * 1024;
        } else {
            int vv = id - 5;
            int c16 = vv * 64 + lane;
            int row = c16 >> 3, seg = (c16 & 7) ^ (row & 7);   // pre-swizzled source
            srcp[s] = VTg + (size_t)(h * DHEAD + row) * vstride + tt0 * KVT + seg * 8;
            sstep[s] = KVT;
            dstoff[s] = KBYTES + vv * 1024;
        }
    }

#define STAGE(BUFOFF)                                                     \
    do {                                                                  \
        _Pragma("unroll")                                                 \
        for (int s = 0; s < 3; ++s) {                                     \
            if (s < nslot) {                                              \
                gld_lds16(srcp[s], smem + (BUFOFF) + dstoff[s]);          \
                srcp[s] += sstep[s];                                      \
            }                                                             \
        }                                                                 \
    } while (0)

    // Q fragments direct from global (d 40..63 pad = zero regs; qf1 zero for g>0)
    bf16x8 qf0 = *(const bf16x8*)(Qg + (size_t)(qb + q) * DIM + h * DHEAD + g * 8);
    bf16x8 qf1 = bzero8();
    if (g == 0) qf1 = *(const bf16x8*)(Qg + (size_t)(qb + q) * DIM + h * DHEAD + 32);

    f32x4 accO[3];
#pragma unroll
    for (int dt = 0; dt < 3; ++dt)
#pragma unroll
        for (int r = 0; r < 4; ++r) accO[dt][r] = 0.f;
    float m_run = -1e30f;

    const int swv = (q & 7) << 4;

#define TILE_BODY(KSC, J0)                                                        \
    do {                                                                          \
        const char* Ks_ = (KSC);                                                  \
        const char* Vs_ = Ks_ + KBYTES;                                           \
        const char* kb0b = Ks_ + q * 80 + g * 16;                                 \
        const char* kb1b = Ks_ + q * 80 + 64;                                     \
        f32x4 s4[4];                                                              \
        __builtin_amdgcn_s_setprio(1);                                            \
        _Pragma("unroll")                                                         \
        for (int jt = 0; jt < 4; ++jt) {                                          \
            bf16x8 kb0 = *(const bf16x8*)(kb0b + jt * 1280);                      \
            bf16x8 kb1 = *(const bf16x8*)(kb1b + jt * 1280);                      \
            f32x4 z;                                                              \
            _Pragma("unroll") for (int r = 0; r < 4; ++r) z[r] = 0.f;             \
            z = __builtin_amdgcn_mfma_f32_16x16x32_bf16(kb0, qf0, z, 0, 0, 0);    \
            z = __builtin_amdgcn_mfma_f32_16x16x32_bf16(kb1, qf1, z, 0, 0, 0);    \
            s4[jt] = z;                                                           \
        }                                                                         \
        __builtin_amdgcn_s_setprio(0);                                            \
        if ((J0) + KVT > nkv) {                                                   \
            _Pragma("unroll") for (int jt = 0; jt < 4; ++jt)                      \
            _Pragma("unroll") for (int r = 0; r < 4; ++r)                         \
                if ((J0) + jt * 16 + g * 4 + r >= nkv) s4[jt][r] = -1e30f;        \
        }                                                                         \
        float mvv0 = fmaxf(fmaxf(fmaxf(s4[0][0], s4[1][0]), s4[2][0]), s4[3][0]); \
        float mvv1 = fmaxf(fmaxf(fmaxf(s4[0][1], s4[1][1]), s4[2][1]), s4[3][1]); \
        float mvv2 = fmaxf(fmaxf(fmaxf(s4[0][2], s4[1][2]), s4[2][2]), s4[3][2]); \
        float mvv3 = fmaxf(fmaxf(fmaxf(s4[0][3], s4[1][3]), s4[2][3]), s4[3][3]); \
        float mt = fmaxf(fmaxf(fmaxf(mvv0, mvv1), mvv2), mvv3);                   \
        mt = fmaxf(mt, __shfl_xor(mt, 16));                                       \
        mt = fmaxf(mt, __shfl_xor(mt, 32));                                       \
        if (!__all(mt <= m_run + 8.f)) {                                          \
            float mnew = fmaxf(m_run, mt);                                        \
            float f = exp2f(m_run - mnew);                                        \
            m_run = mnew;                                                         \
            _Pragma("unroll") for (int dt = 0; dt < 3; ++dt)                      \
            _Pragma("unroll") for (int r = 0; r < 4; ++r) accO[dt][r] *= f;       \
        }                                                                         \
        union PU { bf16x4 hv; shortx4 sv; } pk[4];                                \
        _Pragma("unroll") for (int jt = 0; jt < 4; ++jt) {                        \
            bf16x4 hv;                                                            \
            _Pragma("unroll") for (int r = 0; r < 4; ++r)                         \
                hv[r] = (bf16)exp2f(s4[jt][r] - m_run);                           \
            pk[jt].hv = hv;                                                       \
        }                                                                         \
        __builtin_amdgcn_s_setprio(1);                                            \
        const char* vqb = Vs_ + q * 128;                                          \
        _Pragma("unroll") for (int jt = 0; jt < 4; ++jt) {                        \
            const char* vj = vqb + ((jt * 32 + g * 8) ^ swv);                     \
            _Pragma("unroll") for (int dt = 0; dt < 3; ++dt) {                    \
                shortx4 vb = *(const shortx4*)(vj + dt * 2048);                   \
                accO[dt] = __builtin_amdgcn_mfma_f32_16x16x16bf16_1k(             \
                               vb, pk[jt].sv, accO[dt], 0, 0, 0);                 \
            }                                                                     \
        }                                                                         \
        __builtin_amdgcn_s_setprio(0);                                            \
        __syncthreads();                                                          \
    } while (0)

    STAGE(0);
    __syncthreads();

    int tt = tt0;
    while (tt < tt1) {
        if (tt + 1 < tt1) STAGE(FBUF);
        TILE_BODY(smem, tt * KVT);
        ++tt;
        if (tt >= tt1) break;
        if (tt + 1 < tt1) STAGE(0);
        TILE_BODY(smem + FBUF, tt * KVT);
        ++tt;
    }
#undef TILE_BODY
#undef STAGE

    // l = O^T row 40 (ones row), held by lane 32+q at accO[2][0]
    float l = __shfl(accO[2][0], 32 + q);

    if (DIRECT) {
        float inv = 1.f / l;
#pragma unroll
        for (int dt = 0; dt < 3; ++dt) {
            if (dt < 2 || g < 2) {
                bf16x4 o;
#pragma unroll
                for (int r = 0; r < 4; ++r) o[r] = (bf16)(accO[dt][r] * inv);
                *(bf16x4*)(O + (size_t)(qb + q) * DIM + h * DHEAD + dt * 16 + g * 4) = o;
            }
        }
    } else {
        size_t rowi = (size_t)(split * HEADS + h) * NTOK + qb + q;
#pragma unroll
        for (int dt = 0; dt < 3; ++dt) {
            if (dt < 2 || g < 2) {
                bf16x4 o;
#pragma unroll
                for (int r = 0; r < 4; ++r) o[r] = (bf16)accO[dt][r];
                *(bf16x4*)(Opart + rowi * 40 + dt * 16 + g * 4) = o;
            }
        }
        if (g == 2) {
            f32x2 ml;
            ml[0] = m_run; ml[1] = accO[2][0];
            *(f32x2*)(MLpart + rowi * 2) = ml;
        }
    }
}

// ---------------- combine 4 KV-splits (bf16 partials) ----------------
__global__ __launch_bounds__(256)
void flash_combine(const bf16* __restrict__ Opart, const float* __restrict__ MLpart,
                   bf16* __restrict__ O) {
    int idx = blockIdx.x * 256 + threadIdx.x;  // 4096*40
    int qi = idx / 40, c = idx - qi * 40;
    int h = c / 5, c8 = c - h * 5;
    float mv[4], lv[4];
    float M = -1e30f;
#pragma unroll
    for (int s = 0; s < 4; ++s) {
        f32x2 ml = *(const f32x2*)(MLpart + ((size_t)(s * HEADS + h) * NTOK + qi) * 2);
        mv[s] = ml[0]; lv[s] = ml[1];
        M = fmaxf(M, ml[0]);
    }
    float wgt[4], denom = 0.f;
#pragma unroll
    for (int s = 0; s < 4; ++s) { wgt[s] = exp2f(mv[s] - M); denom += wgt[s] * lv[s]; }
    float inv = 1.f / denom;
    float o[8];
#pragma unroll
    for (int e = 0; e < 8; ++e) o[e] = 0.f;
#pragma unroll
    for (int s = 0; s < 4; ++s) {
        bf16x8 op = *(const bf16x8*)(Opart + ((size_t)(s * HEADS + h) * NTOK + qi) * 40 + c8 * 8);
#pragma unroll
        for (int e = 0; e < 8; ++e) o[e] += wgt[s] * (float)op[e];
    }
    bf16x8 ov;
#pragma unroll
    for (int e = 0; e < 8; ++e) ov[e] = (bf16)(o[e] * inv);
    *(bf16x8*)(O + (size_t)qi * DIM + h * DHEAD + c8 * 8) = ov;
}

// ---------------- launch ----------------
extern "C" void kernel_launch(void* const* d_in, const int* in_sizes, int n_in,
                              void* d_out, int out_size, void* d_ws, size_t ws_size,
                              hipStream_t stream) {
    const float* x     = (const float*)d_in[0];
    const float* ctx   = (const float*)d_in[1];
    const float* n1_g  = (const float*)d_in[2];
    const float* n1_b  = (const float*)d_in[3];
    const float* a1_wq = (const float*)d_in[4];
    const float* a1_wk = (const float*)d_in[5];
    const float* a1_wv = (const float*)d_in[6];
    const float* a1_wo = (const float*)d_in[7];
    const float* a1_bo = (const float*)d_in[8];
    const float* n2_g  = (const float*)d_in[9];
    const float* n2_b  = (const float*)d_in[10];
    const float* a2_wq = (const float*)d_in[11];
    const float* a2_wk = (const float*)d_in[12];
    const float* a2_wv = (const float*)d_in[13];
    const float* a2_wo = (const float*)d_in[14];
    const float* a2_bo = (const float*)d_in[15];
    const float* n3_g  = (const float*)d_in[16];
    const float* n3_b  = (const float*)d_in[17];
    const float* ff_w1 = (const float*)d_in[18];
    const float* ff_b1 = (const float*)d_in[19];
    const float* ff_w2 = (const float*)d_in[20];
    const float* ff_b2 = (const float*)d_in[21];

    char* ws = (char*)d_ws;
    size_t off = 0;
    auto alloc = [&](size_t bytes) -> char* {
        char* p = ws + off;
        off += (bytes + 255) & ~(size_t)255;
        return p;
    };
    bf16* lnbuf  = (bf16*)alloc((size_t)NTOK * DIM * 2);
    bf16* qbuf   = (bf16*)alloc((size_t)NTOK * DIM * 2);
    bf16* kbuf   = (bf16*)alloc((size_t)NTOK * DIM * 2);
    bf16* vtbuf  = (bf16*)alloc((size_t)DIM * NTOK * 2);   // [320 d][4096 tok]
    bf16* abuf   = (bf16*)alloc((size_t)NTOK * DIM * 2);
    bf16* hbuf   = (bf16*)alloc((size_t)NTOK * 2 * IFF * 2);  // Opart alias only
    bf16* gbuf   = (bf16*)alloc((size_t)NTOK * IFF * 2);
    bf16* ctxb   = (bf16*)alloc((size_t)NCTX * CTXD * 2);
    bf16* k2buf  = (bf16*)alloc((size_t)128 * DIM * 2);
    bf16* vt2buf = (bf16*)alloc((size_t)DIM * 128 * 2);
    bf16* wqkvT  = (bf16*)alloc((size_t)960 * DIM * 2);
    bf16* woT    = (bf16*)alloc((size_t)DIM * DIM * 2);
    bf16* q2T    = (bf16*)alloc((size_t)DIM * DIM * 2);
    bf16* wkv2T  = (bf16*)alloc((size_t)640 * CTXD * 2);
    bf16* o2T    = (bf16*)alloc((size_t)DIM * DIM * 2);
    bf16* w1T    = (bf16*)alloc((size_t)2 * IFF * DIM * 2);
    bf16* w2T    = (bf16*)alloc((size_t)IFF * DIM * 2);
    float* out   = (float*)d_out;

    bf16*  Opart  = (bf16*)hbuf;    // 4*8*4096*40 bf16 = 10.5 MB
    float* MLpart = (float*)gbuf;   // consumed by combine before FF1 writes gbuf

    // ---- fused preprocessing + LN1 (1 launch) ----
    {
        PreTab P;
        auto set = [&](int i, const float* s, bf16* d, int K, int N, int tile0, int perm) {
            P.j[i].src = s; P.j[i].dst = d; P.j[i].K = K; P.j[i].N = N;
            P.j[i].ntx = N / 32; P.j[i].tile0 = tile0; P.j[i].perm = perm;
        };
        set(0, a1_wq, wqkvT,                        320, 320,    0, 0);
        set(1, a1_wk, wqkvT + (size_t)320 * 320,    320, 320,  100, 0);
        set(2, a1_wv, wqkvT + (size_t)640 * 320,    320, 320,  200, 0);
        set(3, a1_wo, woT,                          320, 320,  300, 0);
        set(4, a2_wq, q2T,                          320, 320,  400, 0);
        set(5, a2_wo, o2T,                          320, 320,  500, 0);
        set(6, a2_wk, wkv2T,                        768, 320,  600, 0);
        set(7, a2_wv, wkv2T + (size_t)320 * 768,    768, 320,  840, 0);
        set(8, ff_w1, w1T,                          320, 2560, 1080, 1);
        set(9, ff_w2, w2T,                          1280, 320, 1880, 0);
        preprocess_all<<<PRE_TILES + CONV_BLOCKS + LN1_BLOCKS, 256, 0, stream>>>(
            P, ctx, ctxb, x, n1_g, n1_b, lnbuf);
    }

    // ---- self-attention ----
    gemm_db<5, 128, 64, 1><<<dim3(32, 15), 256, 0, stream>>>(lnbuf, wqkvT, NTOK, 960, DIM,
                                                             qbuf, kbuf, vtbuf, nullptr, nullptr, nullptr, NTOK);
    flash_attn9<0><<<dim3(64, 8, 4), 256, 0, stream>>>(qbuf, kbuf, vtbuf, nullptr,
                                                       Opart, MLpart, NTOK, NTOK, 16);
    flash_combine<<<640, 256, 0, stream>>>(Opart, MLpart, abuf);
    gemm_db<2, 64, 64, 1><<<dim3(64, 5), 256, 0, stream>>>(abuf, woT, NTOK, DIM, DIM,
                                                           nullptr, nullptr, nullptr, out, a1_bo, x, 0);

    // ---- cross-attention (LN2 + cross-KV fused into one launch) ----
    ln2_plus_cross<<<1034, 256, 0, stream>>>(out, n2_g, n2_b, lnbuf,
                                             ctxb, wkv2T, k2buf, vt2buf, 128);
    gemm_db<4, 64, 64, 1><<<dim3(64, 5), 256, 0, stream>>>(lnbuf, q2T, NTOK, DIM, DIM,
                                                           qbuf, nullptr, nullptr, nullptr, nullptr, nullptr, 0);
    flash_attn9<1><<<dim3(64, 8, 1), 256, 0, stream>>>(qbuf, k2buf, vt2buf, abuf,
                                                       nullptr, nullptr, NCTX, 128, 2);
    gemm_db<2, 64, 64, 1><<<dim3(64, 5), 256, 0, stream>>>(abuf, o2T, NTOK, DIM, DIM,
                                                           nullptr, nullptr, nullptr, out, a2_bo, out, 0);

    // ---- GEGLU FF (geglu fused into FF1 epilogue) ----
    layernorm_kernel<<<1024, 256, 0, stream>>>(out, n3_g, n3_b, lnbuf);
    gemm_db<7, 128, 64, 1><<<dim3(32, 40), 256, 0, stream>>>(lnbuf, w1T, NTOK, 2 * IFF, DIM,
                                                             gbuf, nullptr, nullptr, nullptr, ff_b1, nullptr, 0);
    gemm_db<2, 64, 64, 1><<<dim3(64, 5), 256, 0, stream>>>(gbuf, w2T, NTOK, DIM, IFF,
                                                           nullptr, nullptr, nullptr, out, ff_b2, out, 0);
}